// Round 1
// baseline (26502.249 us; speedup 1.0000x reference)
//
#include <hip/hip_runtime.h>
#include <math.h>

#define NB 256      // batch
#define NS 128      // encoder len
#define NCOL 64     // columns
#define NT 60       // decode steps
#define DENC 512
#define DRNN 512
#define DATT 512
#define DACT 128
#define DTYP 64
#define DIN 1344    // a_embed(128)|att(512)|fprod(128)|ftype(64)|parent_h(512)
#define DXH 1856    // DIN + RNN (h appended for fused W_ih/W_hh matmul)
#define DG 2048     // 4*RNN
#define NEGV (-1e9f)

__device__ __forceinline__ float sigf(float x) { return 1.0f / (1.0f + expf(-x)); }

// -------------------------------------------------------------------------
__global__ __launch_bounds__(256) void zero_kernel(float* __restrict__ p, int n) {
  int i = blockIdx.x * 256 + threadIdx.x;
  if (i < n) p[i] = 0.0f;
}

// -------------------------------------------------------------------------
// Generic 64x64-tile SGEMM, C[M,N] = act(A[M,K] @ B[K,N] + bias).
// A may be split at column KsA into A1|A2 (concat inputs), B split at row KsB
// into B1|B2 (stacked weights). Splits must be multiples of 16.
// Requires M%64==0, N%64==0, K%16==0. Block 256 threads, 4x4 microtile.
__global__ __launch_bounds__(256) void gemm64(
    const float* __restrict__ A1, const float* __restrict__ A2, int KsA,
    const float* __restrict__ B1, const float* __restrict__ B2, int KsB,
    const float* __restrict__ bias, float* __restrict__ Cm,
    int N, int K, int act)
{
  __shared__ float As[16][68];  // transposed A tile [k][m]
  __shared__ float Bs[16][68];
  int tid = threadIdx.x;
  int arow = tid >> 2, akq = tid & 3;    // A: 64 rows x 4 float4s of k
  int brow = tid >> 4, bnq = tid & 15;   // B: 16 k-rows x 16 float4s of n
  int tx = tid & 15, ty = tid >> 4;
  int mBase = blockIdx.y * 64, nBase = blockIdx.x * 64;
  float acc[4][4] = {};
  for (int kt = 0; kt < K; kt += 16) {
    int m = mBase + arow, k0 = kt + akq * 4;
    float4 a;
    if (k0 < KsA) a = *(const float4*)(A1 + (size_t)m * KsA + k0);
    else          a = *(const float4*)(A2 + (size_t)m * (K - KsA) + (k0 - KsA));
    As[akq * 4 + 0][arow] = a.x; As[akq * 4 + 1][arow] = a.y;
    As[akq * 4 + 2][arow] = a.z; As[akq * 4 + 3][arow] = a.w;
    int gk = kt + brow, n0 = nBase + bnq * 4;
    float4 bv;
    if (gk < KsB) bv = *(const float4*)(B1 + (size_t)gk * N + n0);
    else          bv = *(const float4*)(B2 + (size_t)(gk - KsB) * N + n0);
    *(float4*)&Bs[brow][bnq * 4] = bv;
    __syncthreads();
    #pragma unroll
    for (int kk = 0; kk < 16; ++kk) {
      float av[4], bw[4];
      #pragma unroll
      for (int i = 0; i < 4; ++i) av[i] = As[kk][ty * 4 + i];
      #pragma unroll
      for (int j = 0; j < 4; ++j) bw[j] = Bs[kk][tx * 4 + j];
      #pragma unroll
      for (int i = 0; i < 4; ++i)
        #pragma unroll
        for (int j = 0; j < 4; ++j)
          acc[i][j] = fmaf(av[i], bw[j], acc[i][j]);
    }
    __syncthreads();
  }
  #pragma unroll
  for (int i = 0; i < 4; ++i) {
    int m = mBase + ty * 4 + i;
    #pragma unroll
    for (int j = 0; j < 4; ++j) {
      int n = nBase + tx * 4 + j;
      float v = acc[i][j];
      if (bias) v += bias[n];
      if (act == 1) v = tanhf(v);
      Cm[(size_t)m * N + n] = v;
    }
  }
}

// -------------------------------------------------------------------------
// Build xh[b][1856] = [a_embed | att_tm1 | prod_embed[fprod] | type_embed[ftype]
//                      | parent_h | h_tm1]; zero the x part (first 1344) at t==0.
__global__ __launch_bounds__(256) void build_x_kernel(
    float* __restrict__ xh, const float* __restrict__ hist,
    const float* __restrict__ h, const float* __restrict__ att,
    const float* __restrict__ colin, const float* __restrict__ prod_embed,
    const float* __restrict__ type_embed,
    const int* __restrict__ action_kind, const int* __restrict__ prod_ids,
    const int* __restrict__ col_ids, const int* __restrict__ parent_prod,
    const int* __restrict__ parent_type, const int* __restrict__ parent_time,
    const int* __restrict__ tgt_lens, int t)
{
  int b = blockIdx.x, tid = threadIdx.x;
  int kp = 0, pp = 0, cp = 0;
  if (t > 0) {
    kp = action_kind[b * NT + t - 1];
    pp = prod_ids[b * NT + t - 1];
    cp = col_ids[b * NT + t - 1];
  }
  bool pv = (t - 1) < tgt_lens[b];
  int fp = parent_prod[b * NT + t];
  int ft = parent_type[b * NT + t];
  int ptm = parent_time[b * NT + t];
  float* dst = xh + (size_t)b * DXH;
  for (int j = tid; j < DXH; j += 256) {
    float v;
    if (j < DACT) {
      if (kp == 2) v = colin[((size_t)b * NCOL + cp) * DACT + j];
      else { int r = (kp == 1) ? 97 : pp; v = prod_embed[r * DACT + j]; }
      if (!pv) v = 0.0f;
    } else if (j < 640) {
      v = att[b * DATT + (j - 128)];
    } else if (j < 768) {
      v = prod_embed[fp * DACT + (j - 640)];
    } else if (j < 832) {
      v = type_embed[ft * DTYP + (j - 768)];
    } else if (j < DIN) {
      v = hist[((size_t)ptm * NB + b) * DRNN + (j - 832)];
    } else {
      dst[j] = h[b * DRNN + (j - DIN)];
      continue;
    }
    dst[j] = (t == 0) ? 0.0f : v;
  }
}

// -------------------------------------------------------------------------
__global__ __launch_bounds__(256) void lstm_kernel(
    const float* __restrict__ gates, float* __restrict__ c,
    float* __restrict__ h, float* __restrict__ hist, int t)
{
  int idx = blockIdx.x * 256 + threadIdx.x;  // 0 .. NB*DRNN-1
  int b = idx >> 9, j = idx & 511;
  const float* g = gates + (size_t)b * DG;
  float iv = g[j], fv = g[512 + j], gv = g[1024 + j], ov = g[1536 + j];
  float cn = sigf(fv) * c[idx] + sigf(iv) * tanhf(gv);
  float hn = sigf(ov) * tanhf(cn);
  c[idx] = cn;
  h[idx] = hn;
  hist[(size_t)t * (NB * DRNN) + idx] = hn;
}

// -------------------------------------------------------------------------
// scores = attq . enc (masked), softmax over S, ctx = p . enc. One block per b.
__global__ __launch_bounds__(256) void attn_kernel(
    const float* __restrict__ enc, const float* __restrict__ attq,
    const int* __restrict__ enc_lens, float* __restrict__ ctx)
{
  int b = blockIdx.x, tid = threadIdx.x;
  __shared__ float q[DENC];
  __shared__ float sc[NS];
  __shared__ float sred[2];
  for (int j = tid; j < DENC; j += 256) q[j] = attq[b * DENC + j];
  __syncthreads();
  int wave = tid >> 6, lane = tid & 63;
  int el = enc_lens[b];
  const float* eb = enc + (size_t)b * NS * DENC;
  for (int s = wave; s < NS; s += 4) {
    const float* e = eb + (size_t)s * DENC;
    float a = 0.0f;
    #pragma unroll
    for (int u = 0; u < 8; ++u) { int d = u * 64 + lane; a = fmaf(e[d], q[d], a); }
    #pragma unroll
    for (int off = 32; off > 0; off >>= 1) a += __shfl_down(a, off);
    if (lane == 0) sc[s] = (s < el) ? a : NEGV;
  }
  __syncthreads();
  if (tid < 64) {
    float m = fmaxf(sc[tid], sc[tid + 64]);
    #pragma unroll
    for (int off = 32; off > 0; off >>= 1) m = fmaxf(m, __shfl_down(m, off));
    m = __shfl(m, 0);
    float s = expf(sc[tid] - m) + expf(sc[tid + 64] - m);
    #pragma unroll
    for (int off = 32; off > 0; off >>= 1) s += __shfl_down(s, off);
    if (tid == 0) { sred[0] = m; sred[1] = s; }
  }
  __syncthreads();
  float m = sred[0], inv = 1.0f / sred[1];
  if (tid < NS) sc[tid] = expf(sc[tid] - m);
  __syncthreads();
  #pragma unroll
  for (int half = 0; half < 2; ++half) {
    int d = half * 256 + tid;
    float a = 0.0f;
    for (int s = 0; s < NS; ++s) a = fmaf(sc[s], eb[(size_t)s * DENC + d], a);
    ctx[(size_t)b * DENC + d] = a * inv;
  }
}

// -------------------------------------------------------------------------
// Rule log-softmax + pointer net + gold log-prob accumulation + appear update.
__global__ __launch_bounds__(256) void final_step_kernel(
    const float* __restrict__ embq, const float* __restrict__ prod_embed,
    const float* __restrict__ b_lin, const float* __restrict__ att,
    const float* __restrict__ ptrq, const float* __restrict__ col_enc,
    const float* __restrict__ w_mem, const int* __restrict__ col_lens,
    const int* __restrict__ tgt_lens, const int* __restrict__ action_kind,
    const int* __restrict__ prod_ids, const int* __restrict__ col_ids,
    float* __restrict__ appear, float* __restrict__ acc, int t)
{
  int b = blockIdx.x, tid = threadIdx.x;
  __shared__ float eq[DACT], pq[DATT], av[DATT];
  __shared__ float logits[98];
  __shared__ float wl[NCOL];
  __shared__ float sgate;
  if (tid < DACT) eq[tid] = embq[b * DACT + tid];
  for (int j = tid; j < DATT; j += 256) {
    pq[j] = ptrq[b * DATT + j];
    av[j] = att[b * DATT + j];
  }
  __syncthreads();
  // rule logits (PTEMP==1)
  if (tid < 98) {
    const float* pr = prod_embed + tid * DACT;
    float a = 0.0f;
    #pragma unroll 8
    for (int k = 0; k < DACT; ++k) a = fmaf(eq[k], pr[k], a);
    logits[tid] = a + b_lin[tid];
  }
  // pointer scores: w_c[c] = ptrq . col_enc[b,c]
  {
    int wave = tid >> 6, lane = tid & 63;
    const float* cb = col_enc + (size_t)b * NCOL * 512;
    for (int ci = wave; ci < NCOL; ci += 4) {
      const float* e = cb + (size_t)ci * 512;
      float a = 0.0f;
      #pragma unroll
      for (int u = 0; u < 8; ++u) { int d = u * 64 + lane; a = fmaf(e[d], pq[d], a); }
      #pragma unroll
      for (int off = 32; off > 0; off >>= 1) a += __shfl_down(a, off);
      if (lane == 0) wl[ci] = a;
    }
  }
  // memory gate = sigmoid(att . w_mem)
  if (tid < 64) {
    float a = 0.0f;
    #pragma unroll
    for (int u = 0; u < 8; ++u) { int d = u * 64 + tid; a = fmaf(av[d], w_mem[d], a); }
    #pragma unroll
    for (int off = 32; off > 0; off >>= 1) a += __shfl_down(a, off);
    if (tid == 0) sgate = sigf(a);
  }
  __syncthreads();
  if (tid < 64) {
    // rule logsumexp over 98
    float m = logits[tid];
    if (tid + 64 < 98) m = fmaxf(m, logits[tid + 64]);
    #pragma unroll
    for (int off = 32; off > 0; off >>= 1) m = fmaxf(m, __shfl_down(m, off));
    m = __shfl(m, 0);
    float s = expf(logits[tid] - m) + ((tid + 64 < 98) ? expf(logits[tid + 64] - m) : 0.0f);
    #pragma unroll
    for (int off = 32; off > 0; off >>= 1) s += __shfl_down(s, off);
    s = __shfl(s, 0);
    float lseR = m + logf(s);
    // pointer weights with appear/gate mixing (CTEMP==1); appear read BEFORE update
    int clen = col_lens[b];
    float gate = sgate;
    float ap = appear[b * NCOL + tid];
    float w = wl[tid] * (ap * gate + (1.0f - ap) * (1.0f - gate));
    w = (tid < clen) ? w : NEGV;
    wl[tid] = w;
    float m2 = w;
    #pragma unroll
    for (int off = 32; off > 0; off >>= 1) m2 = fmaxf(m2, __shfl_down(m2, off));
    m2 = __shfl(m2, 0);
    float s2 = expf(w - m2);
    #pragma unroll
    for (int off = 32; off > 0; off >>= 1) s2 += __shfl_down(s2, off);
    s2 = __shfl(s2, 0);
    float lse2 = m2 + logf(s2);
    float csum = (tid < clen) ? (w - lse2) : 0.0f;
    #pragma unroll
    for (int off = 32; off > 0; off >>= 1) csum += __shfl_down(csum, off);
    if (tid == 0) {
      int kind = action_kind[b * NT + t];
      int pid = prod_ids[b * NT + t];
      int cid = col_ids[b * NT + t];
      bool valid = (t < tgt_lens[b]);
      int gj = (kind == 1) ? 97 : pid;
      float lp_rule = logits[gj] - lseR;
      float lp_col = 0.8f * (wl[cid] - lse2) + 0.2f * csum / (float)clen;
      float lp = (kind == 2) ? lp_col : lp_rule;
      if (valid) acc[b] += lp;
      if (kind == 2 && valid)
        appear[b * NCOL + cid] = fmaxf(appear[b * NCOL + cid], 1.0f);
    }
  }
}

// -------------------------------------------------------------------------
__global__ __launch_bounds__(256) void loss_kernel(const float* __restrict__ acc,
                                                   float* __restrict__ out) {
  int tid = threadIdx.x;
  float v = acc[tid];
  #pragma unroll
  for (int off = 32; off > 0; off >>= 1) v += __shfl_down(v, off);
  __shared__ float part[4];
  if ((tid & 63) == 0) part[tid >> 6] = v;
  __syncthreads();
  if (tid == 0) out[0] = -(part[0] + part[1] + part[2] + part[3]) * (1.0f / NB);
}

// -------------------------------------------------------------------------
extern "C" void kernel_launch(void* const* d_in, const int* in_sizes, int n_in,
                              void* d_out, int out_size, void* d_ws, size_t ws_size,
                              hipStream_t stream) {
  const float* enc         = (const float*)d_in[0];
  const float* col_enc     = (const float*)d_in[1];
  const int*   enc_lens    = (const int*)d_in[2];
  const int*   col_lens    = (const int*)d_in[3];
  const int*   action_kind = (const int*)d_in[4];
  const int*   tgt_lens    = (const int*)d_in[5];
  const int*   prod_ids    = (const int*)d_in[6];
  const int*   col_ids     = (const int*)d_in[7];
  const int*   parent_prod = (const int*)d_in[8];
  const int*   parent_type = (const int*)d_in[9];
  const int*   parent_time = (const int*)d_in[10];
  const float* prod_embed  = (const float*)d_in[11];
  const float* type_embed  = (const float*)d_in[12];
  const float* b_lin       = (const float*)d_in[13];
  const float* W_ih        = (const float*)d_in[14];
  const float* W_hh        = (const float*)d_in[15];
  const float* b_lstm      = (const float*)d_in[16];
  const float* W_att_q     = (const float*)d_in[17];
  const float* W_att_vec   = (const float*)d_in[18];
  const float* W_r1        = (const float*)d_in[19];
  const float* b_r1        = (const float*)d_in[20];
  const float* W_r2        = (const float*)d_in[21];
  const float* b_r2        = (const float*)d_in[22];
  const float* W_col_in    = (const float*)d_in[23];
  const float* W_ptr       = (const float*)d_in[24];
  const float* w_mem       = (const float*)d_in[25];

  float* ws = (float*)d_ws;
  size_t off = 0;
  float* h      = ws + off; off += NB * DRNN;            // 131072
  float* c      = ws + off; off += NB * DRNN;
  float* att    = ws + off; off += NB * DATT;
  float* appear = ws + off; off += NB * NCOL;            // 16384
  float* acc    = ws + off; off += NB;                   // 256
  int zeroN = (int)off;                                  // 409856 floats
  float* hist  = ws + off; off += (size_t)NT * NB * DRNN; // 7.86M
  float* colin = ws + off; off += (size_t)NB * NCOL * DACT; // 2.10M
  float* xh    = ws + off; off += (size_t)NB * DXH;      // 475136
  float* gates = ws + off; off += (size_t)NB * DG;       // 524288
  // aliased scratch (temporally disjoint within a step):
  float* attq = xh;                // used K4->K5, xh dead after gates GEMM
  float* ctx  = xh + NB * DENC;    // used K5->K6
  float* ptrq = xh + 2 * NB * DENC;
  float* embq = xh + 3 * NB * DENC;  // 32768 <= remaining 81920
  float* embh = gates;             // used K7->K8, gates dead after lstm
  (void)ws_size; (void)in_sizes; (void)n_in; (void)out_size;

  // zero persistent state
  zero_kernel<<<(zeroN + 255) / 256, 256, 0, stream>>>(ws, zeroN);
  // col_in_embed = col_enc @ W_col_in  (M=16384, K=512, N=128)
  gemm64<<<dim3(2, 256), 256, 0, stream>>>(col_enc, nullptr, 512,
      W_col_in, nullptr, 512, nullptr, colin, 128, 512, 0);

  for (int t = 0; t < NT; ++t) {
    build_x_kernel<<<NB, 256, 0, stream>>>(xh, hist, h, att, colin, prod_embed,
        type_embed, action_kind, prod_ids, col_ids, parent_prod, parent_type,
        parent_time, tgt_lens, t);
    // gates = [x|h] @ [W_ih;W_hh] + b_lstm  (M=256, K=1856, N=2048)
    gemm64<<<dim3(32, 4), 256, 0, stream>>>(xh, nullptr, DXH,
        W_ih, W_hh, DIN, b_lstm, gates, DG, DXH, 0);
    lstm_kernel<<<NB * DRNN / 256, 256, 0, stream>>>(gates, c, h, hist, t);
    // attq = h_new @ W_att_q  (256x512x512)
    gemm64<<<dim3(8, 4), 256, 0, stream>>>(h, nullptr, 512,
        W_att_q, nullptr, 512, nullptr, attq, 512, 512, 0);
    attn_kernel<<<NB, 256, 0, stream>>>(enc, attq, enc_lens, ctx);
    // att_new = tanh([ctx|h] @ W_att_vec)  (256x1024x512)
    gemm64<<<dim3(8, 4), 256, 0, stream>>>(ctx, h, 512,
        W_att_vec, nullptr, 1024, nullptr, att, 512, 1024, 1);
    // embh = tanh(att @ W_r1 + b_r1)  (256x512x2048)
    gemm64<<<dim3(32, 4), 256, 0, stream>>>(att, nullptr, 512,
        W_r1, nullptr, 512, b_r1, embh, DG, 512, 1);
    // embq = embh @ W_r2 + b_r2  (256x2048x128)
    gemm64<<<dim3(2, 4), 256, 0, stream>>>(embh, nullptr, DG,
        W_r2, nullptr, DG, b_r2, embq, 128, DG, 0);
    // ptrq = att @ W_ptr  (256x512x512)
    gemm64<<<dim3(8, 4), 256, 0, stream>>>(att, nullptr, 512,
        W_ptr, nullptr, 512, nullptr, ptrq, 512, 512, 0);
    final_step_kernel<<<NB, 256, 0, stream>>>(embq, prod_embed, b_lin, att,
        ptrq, col_enc, w_mem, col_lens, tgt_lens, action_kind, prod_ids,
        col_ids, appear, acc, t);
  }
  loss_kernel<<<1, 256, 0, stream>>>(acc, (float*)d_out);
}

// Round 2
// 9103.402 us; speedup vs baseline: 2.9112x; 2.9112x over previous
//
#include <hip/hip_runtime.h>
#include <math.h>

#define NB 256      // batch
#define NS 128      // encoder len
#define NCOL 64     // columns
#define NT 60       // decode steps
#define DENC 512
#define DRNN 512
#define DATT 512
#define DACT 128
#define DTYP 64
#define DIN 1344    // a_embed(128)|att(512)|fprod(128)|ftype(64)|parent_h(512)
#define DXH 1856    // DIN + RNN
#define DG 2048     // 4*RNN
#define NEGV (-1e9f)

typedef unsigned short ushort_t;
typedef __attribute__((ext_vector_type(8))) short short8;
typedef __attribute__((ext_vector_type(4))) float f32x4;

__device__ __forceinline__ float sigf(float x) { return 1.0f / (1.0f + expf(-x)); }

__device__ __forceinline__ ushort_t f2bf(float f) {
  union { float f; unsigned u; } v; v.f = f;
  unsigned r = v.u + 0x7fffu + ((v.u >> 16) & 1u);  // RNE
  return (ushort_t)(r >> 16);
}
__device__ __forceinline__ float bf2f(ushort_t b) {
  union { unsigned u; float f; } v; v.u = ((unsigned)b) << 16; return v.f;
}

// -------------------------------------------------------------------------
__global__ __launch_bounds__(256) void zero_kernel(float* __restrict__ p, int n) {
  int i = blockIdx.x * 256 + threadIdx.x;
  if (i < n) p[i] = 0.0f;
}

// -------------------------------------------------------------------------
// Pack f32 weight sub-rect into MFMA-fragment-friendly bf16 layout:
// dst[((K0+k)/8)*Ntot + (N0+n)]*8 + (K0+k)%8
__global__ __launch_bounds__(256) void pack_w(const float* __restrict__ src,
    ushort_t* __restrict__ dst, int Ksub, int Nsub, int Ntot, int K0, int N0, int ldsrc)
{
  int idx = blockIdx.x * 256 + threadIdx.x;
  if (idx >= Ksub * Nsub) return;
  int k = idx / Nsub, n = idx - k * Nsub;
  int gk = K0 + k;
  dst[((size_t)(gk >> 3) * Ntot + (N0 + n)) * 8 + (gk & 7)] =
      f2bf(src[(size_t)k * ldsrc + n]);
}

// -------------------------------------------------------------------------
// MFMA bf16 GEMM: C[M,N] = act(A[M,K] @ B[K,N] + bias), A f32 (split at KsA),
// B pre-packed bf16 [(K/8)][N][8]. Tile 64x64, BK=64, 4 waves (2x2 of 32x32).
// tanh applied for col<actN; bias added for col<biasN. Writes f32 C and/or bf16 Cb.
__global__ __launch_bounds__(256) void gemm_bf16(
    const float* __restrict__ A1, const float* __restrict__ A2, int KsA,
    int lda1, int lda2,
    const ushort_t* __restrict__ Bp,
    const float* __restrict__ bias, int biasN,
    float* __restrict__ C, ushort_t* __restrict__ Cb, int ldc,
    int N, int K, int actN)
{
  __shared__ short As[2][4096];  // [(kc*64+m)*8+e], kc=k-oct within BK=64
  __shared__ short Bs[2][4096];
  const int tid = threadIdx.x;
  const int lane = tid & 63, w = tid >> 6;
  const int wr = w >> 1, wc = w & 1;
  const int mBase = blockIdx.y * 64, nBase = blockIdx.x * 64;
  const int nt = K >> 6;

  f32x4 ra0[2], ra1[2];
  short8 rb[2];

  auto issueA = [&](int kt) {
    #pragma unroll
    for (int s = 0; s < 2; ++s) {
      int slot = tid + s * 256;
      int kc = slot >> 6, m = slot & 63;
      int k0 = kt + kc * 8;
      const float* p;
      if (k0 < KsA) p = A1 + (size_t)(mBase + m) * lda1 + k0;
      else          p = A2 + (size_t)(mBase + m) * lda2 + (k0 - KsA);
      ra0[s] = *(const f32x4*)p;
      ra1[s] = *(const f32x4*)(p + 4);
    }
  };
  auto issueB = [&](int kt) {
    #pragma unroll
    for (int s = 0; s < 2; ++s) {
      int slot = tid + s * 256;
      int kc = slot >> 6, n = slot & 63;
      rb[s] = *(const short8*)(Bp + ((size_t)((kt >> 3) + kc) * N + nBase + n) * 8);
    }
  };
  auto writeS = [&](int buf) {
    #pragma unroll
    for (int s = 0; s < 2; ++s) {
      int slot = tid + s * 256;
      short8 av;
      av[0] = (short)f2bf(ra0[s][0]); av[1] = (short)f2bf(ra0[s][1]);
      av[2] = (short)f2bf(ra0[s][2]); av[3] = (short)f2bf(ra0[s][3]);
      av[4] = (short)f2bf(ra1[s][0]); av[5] = (short)f2bf(ra1[s][1]);
      av[6] = (short)f2bf(ra1[s][2]); av[7] = (short)f2bf(ra1[s][3]);
      *(short8*)&As[buf][slot * 8] = av;
      *(short8*)&Bs[buf][slot * 8] = rb[s];
    }
  };

  f32x4 z4 = {0.f, 0.f, 0.f, 0.f};
  f32x4 acc[2][2] = {{z4, z4}, {z4, z4}};

  auto compute = [&](int buf) {
    #pragma unroll
    for (int kk = 0; kk < 2; ++kk) {
      int ko = kk * 4 + (lane >> 4);
      short8 af[2], bfr[2];
      #pragma unroll
      for (int f = 0; f < 2; ++f) {
        int row = wr * 32 + f * 16 + (lane & 15);
        af[f] = *(const short8*)&As[buf][(ko * 64 + row) * 8];
        int col = wc * 32 + f * 16 + (lane & 15);
        bfr[f] = *(const short8*)&Bs[buf][(ko * 64 + col) * 8];
      }
      #pragma unroll
      for (int i = 0; i < 2; ++i)
        #pragma unroll
        for (int j = 0; j < 2; ++j)
          acc[i][j] = __builtin_amdgcn_mfma_f32_16x16x32_bf16(af[i], bfr[j], acc[i][j], 0, 0, 0);
    }
  };

  issueA(0); issueB(0); writeS(0);
  __syncthreads();
  int cur = 0;
  for (int t = 0; t < nt; ++t) {
    bool more = (t + 1 < nt);
    if (more) { issueA((t + 1) << 6); issueB((t + 1) << 6); }  // loads in flight
    compute(cur);                                               // MFMA on current
    if (more) writeS(cur ^ 1);                                  // write-late (T14)
    __syncthreads();
    cur ^= 1;
  }

  #pragma unroll
  for (int i = 0; i < 2; ++i)
    #pragma unroll
    for (int j = 0; j < 2; ++j)
      #pragma unroll
      for (int r = 0; r < 4; ++r) {
        int row = mBase + wr * 32 + i * 16 + (lane >> 4) * 4 + r;
        int col = nBase + wc * 32 + j * 16 + (lane & 15);
        float v = acc[i][j][r];
        if (col < biasN) v += bias[col];
        if (col < actN) v = tanhf(v);
        if (C)  C[(size_t)row * ldc + col] = v;
        if (Cb) Cb[(size_t)row * ldc + col] = f2bf(v);
      }
}

// -------------------------------------------------------------------------
__global__ __launch_bounds__(256) void build_x_kernel(
    float* __restrict__ xh, const ushort_t* __restrict__ hist,
    const float* __restrict__ h, const float* __restrict__ att,
    const ushort_t* __restrict__ colin, const float* __restrict__ prod_embed,
    const float* __restrict__ type_embed,
    const int* __restrict__ action_kind, const int* __restrict__ prod_ids,
    const int* __restrict__ col_ids, const int* __restrict__ parent_prod,
    const int* __restrict__ parent_type, const int* __restrict__ parent_time,
    const int* __restrict__ tgt_lens, int t)
{
  int b = blockIdx.x, tid = threadIdx.x;
  int kp = 0, pp = 0, cp = 0;
  if (t > 0) {
    kp = action_kind[b * NT + t - 1];
    pp = prod_ids[b * NT + t - 1];
    cp = col_ids[b * NT + t - 1];
  }
  bool pv = (t - 1) < tgt_lens[b];
  int fp = parent_prod[b * NT + t];
  int ft = parent_type[b * NT + t];
  int ptm = parent_time[b * NT + t];
  float* dst = xh + (size_t)b * DXH;
  for (int j = tid; j < DXH; j += 256) {
    float v;
    if (j < DACT) {
      if (kp == 2) v = bf2f(colin[((size_t)b * NCOL + cp) * DACT + j]);
      else { int r = (kp == 1) ? 97 : pp; v = prod_embed[r * DACT + j]; }
      if (!pv) v = 0.0f;
    } else if (j < 640) {
      v = att[b * DATT + (j - 128)];
    } else if (j < 768) {
      v = prod_embed[fp * DACT + (j - 640)];
    } else if (j < 832) {
      v = type_embed[ft * DTYP + (j - 768)];
    } else if (j < DIN) {
      v = bf2f(hist[((size_t)ptm * NB + b) * DRNN + (j - 832)]);
    } else {
      dst[j] = h[b * DRNN + (j - DIN)];
      continue;
    }
    dst[j] = (t == 0) ? 0.0f : v;
  }
}

// -------------------------------------------------------------------------
__global__ __launch_bounds__(256) void lstm_kernel(
    const float* __restrict__ gates, float* __restrict__ c,
    float* __restrict__ h, ushort_t* __restrict__ hist, int t)
{
  int idx = blockIdx.x * 256 + threadIdx.x;
  int b = idx >> 9, j = idx & 511;
  const float* g = gates + (size_t)b * DG;
  float iv = g[j], fv = g[512 + j], gv = g[1024 + j], ov = g[1536 + j];
  float cn = sigf(fv) * c[idx] + sigf(iv) * tanhf(gv);
  float hn = sigf(ov) * tanhf(cn);
  c[idx] = cn;
  h[idx] = hn;
  hist[(size_t)t * (NB * DRNN) + idx] = f2bf(hn);
}

// -------------------------------------------------------------------------
// Online-softmax attention, single pass over valid enc rows. Block = one b.
__global__ __launch_bounds__(256) void attn_kernel(
    const float* __restrict__ enc, const float* __restrict__ attq,
    const int* __restrict__ enc_lens, float* __restrict__ ctx)
{
  int b = blockIdx.x, tid = threadIdx.x;
  int w = tid >> 6, lane = tid & 63;
  int el = enc_lens[b];
  float q[8];
  const float* qp = attq + (size_t)b * DENC + lane * 8;
  #pragma unroll
  for (int j = 0; j < 8; ++j) q[j] = qp[j];
  float m = -1e30f, lr = 0.f;
  float cacc[8];
  #pragma unroll
  for (int j = 0; j < 8; ++j) cacc[j] = 0.f;
  const float* eb = enc + (size_t)b * NS * DENC + lane * 8;
  for (int s = w; s < el; s += 4) {
    const float* e = eb + (size_t)s * DENC;
    float ev[8];
    #pragma unroll
    for (int j = 0; j < 8; ++j) ev[j] = e[j];
    float d = 0.f;
    #pragma unroll
    for (int j = 0; j < 8; ++j) d = fmaf(ev[j], q[j], d);
    #pragma unroll
    for (int off = 32; off > 0; off >>= 1) d += __shfl_xor(d, off);
    float mn = fmaxf(m, d);
    float r = expf(m - mn), p = expf(d - mn);
    lr = lr * r + p;
    #pragma unroll
    for (int j = 0; j < 8; ++j) cacc[j] = cacc[j] * r + p * ev[j];
    m = mn;
  }
  __shared__ float ml[4][2];
  __shared__ float cs[4][DENC];
  if (lane == 0) { ml[w][0] = m; ml[w][1] = lr; }
  #pragma unroll
  for (int j = 0; j < 8; ++j) cs[w][lane * 8 + j] = cacc[j];
  __syncthreads();
  float M = fmaxf(fmaxf(ml[0][0], ml[1][0]), fmaxf(ml[2][0], ml[3][0]));
  float f0 = expf(ml[0][0] - M), f1 = expf(ml[1][0] - M);
  float f2 = expf(ml[2][0] - M), f3 = expf(ml[3][0] - M);
  float invL = 1.f / (f0 * ml[0][1] + f1 * ml[1][1] + f2 * ml[2][1] + f3 * ml[3][1]);
  #pragma unroll
  for (int rep = 0; rep < 2; ++rep) {
    int d = tid + rep * 256;
    ctx[(size_t)b * DENC + d] =
        (f0 * cs[0][d] + f1 * cs[1][d] + f2 * cs[2][d] + f3 * cs[3][d]) * invL;
  }
}

// -------------------------------------------------------------------------
__global__ __launch_bounds__(256) void final_step_kernel(
    const float* __restrict__ embq, const float* __restrict__ prod_embed,
    const float* __restrict__ b_lin, const float* __restrict__ att,
    const float* __restrict__ r1out, const float* __restrict__ col_enc,
    const float* __restrict__ w_mem, const int* __restrict__ col_lens,
    const int* __restrict__ tgt_lens, const int* __restrict__ action_kind,
    const int* __restrict__ prod_ids, const int* __restrict__ col_ids,
    float* __restrict__ appear, float* __restrict__ acc, int t)
{
  int b = blockIdx.x, tid = threadIdx.x;
  __shared__ float eq[DACT], pq[DATT], av[DATT];
  __shared__ float logits[98];
  __shared__ float wl[NCOL];
  __shared__ float sgate;
  if (tid < DACT) eq[tid] = embq[b * DACT + tid];
  for (int j = tid; j < DATT; j += 256) {
    pq[j] = r1out[(size_t)b * 2560 + 2048 + j];  // ptrq slice of fused r1|ptr out
    av[j] = att[b * DATT + j];
  }
  __syncthreads();
  if (tid < 98) {
    const float* pr = prod_embed + tid * DACT;
    float a = 0.0f;
    #pragma unroll 8
    for (int k = 0; k < DACT; ++k) a = fmaf(eq[k], pr[k], a);
    logits[tid] = a + b_lin[tid];
  }
  {
    int wave = tid >> 6, lane = tid & 63;
    const float* cb = col_enc + (size_t)b * NCOL * 512;
    for (int ci = wave; ci < NCOL; ci += 4) {
      const float* e = cb + (size_t)ci * 512;
      float a = 0.0f;
      #pragma unroll
      for (int u = 0; u < 8; ++u) { int d = u * 64 + lane; a = fmaf(e[d], pq[d], a); }
      #pragma unroll
      for (int off = 32; off > 0; off >>= 1) a += __shfl_down(a, off);
      if (lane == 0) wl[ci] = a;
    }
  }
  if (tid < 64) {
    float a = 0.0f;
    #pragma unroll
    for (int u = 0; u < 8; ++u) { int d = u * 64 + tid; a = fmaf(av[d], w_mem[d], a); }
    #pragma unroll
    for (int off = 32; off > 0; off >>= 1) a += __shfl_down(a, off);
    if (tid == 0) sgate = sigf(a);
  }
  __syncthreads();
  if (tid < 64) {
    float m = logits[tid];
    if (tid + 64 < 98) m = fmaxf(m, logits[tid + 64]);
    #pragma unroll
    for (int off = 32; off > 0; off >>= 1) m = fmaxf(m, __shfl_down(m, off));
    m = __shfl(m, 0);
    float s = expf(logits[tid] - m) + ((tid + 64 < 98) ? expf(logits[tid + 64] - m) : 0.0f);
    #pragma unroll
    for (int off = 32; off > 0; off >>= 1) s += __shfl_down(s, off);
    s = __shfl(s, 0);
    float lseR = m + logf(s);
    int clen = col_lens[b];
    float gate = sgate;
    float ap = appear[b * NCOL + tid];
    float wv = wl[tid] * (ap * gate + (1.0f - ap) * (1.0f - gate));
    wv = (tid < clen) ? wv : NEGV;
    wl[tid] = wv;
    float m2 = wv;
    #pragma unroll
    for (int off = 32; off > 0; off >>= 1) m2 = fmaxf(m2, __shfl_down(m2, off));
    m2 = __shfl(m2, 0);
    float s2 = expf(wv - m2);
    #pragma unroll
    for (int off = 32; off > 0; off >>= 1) s2 += __shfl_down(s2, off);
    s2 = __shfl(s2, 0);
    float lse2 = m2 + logf(s2);
    float csum = (tid < clen) ? (wv - lse2) : 0.0f;
    #pragma unroll
    for (int off = 32; off > 0; off >>= 1) csum += __shfl_down(csum, off);
    if (tid == 0) {
      int kind = action_kind[b * NT + t];
      int pid = prod_ids[b * NT + t];
      int cid = col_ids[b * NT + t];
      bool valid = (t < tgt_lens[b]);
      int gj = (kind == 1) ? 97 : pid;
      float lp_rule = logits[gj] - lseR;
      float lp_col = 0.8f * (wl[cid] - lse2) + 0.2f * csum / (float)clen;
      float lp = (kind == 2) ? lp_col : lp_rule;
      if (valid) acc[b] += lp;
      if (kind == 2 && valid)
        appear[b * NCOL + cid] = fmaxf(appear[b * NCOL + cid], 1.0f);
    }
  }
}

// -------------------------------------------------------------------------
__global__ __launch_bounds__(256) void loss_kernel(const float* __restrict__ acc,
                                                   float* __restrict__ out) {
  int tid = threadIdx.x;
  float v = acc[tid];
  #pragma unroll
  for (int off = 32; off > 0; off >>= 1) v += __shfl_down(v, off);
  __shared__ float part[4];
  if ((tid & 63) == 0) part[tid >> 6] = v;
  __syncthreads();
  if (tid == 0) out[0] = -(part[0] + part[1] + part[2] + part[3]) * (1.0f / NB);
}

// -------------------------------------------------------------------------
extern "C" void kernel_launch(void* const* d_in, const int* in_sizes, int n_in,
                              void* d_out, int out_size, void* d_ws, size_t ws_size,
                              hipStream_t stream) {
  const float* enc         = (const float*)d_in[0];
  const float* col_enc     = (const float*)d_in[1];
  const int*   enc_lens    = (const int*)d_in[2];
  const int*   col_lens    = (const int*)d_in[3];
  const int*   action_kind = (const int*)d_in[4];
  const int*   tgt_lens    = (const int*)d_in[5];
  const int*   prod_ids    = (const int*)d_in[6];
  const int*   col_ids     = (const int*)d_in[7];
  const int*   parent_prod = (const int*)d_in[8];
  const int*   parent_type = (const int*)d_in[9];
  const int*   parent_time = (const int*)d_in[10];
  const float* prod_embed  = (const float*)d_in[11];
  const float* type_embed  = (const float*)d_in[12];
  const float* b_lin       = (const float*)d_in[13];
  const float* W_ih        = (const float*)d_in[14];
  const float* W_hh        = (const float*)d_in[15];
  const float* b_lstm      = (const float*)d_in[16];
  const float* W_att_q     = (const float*)d_in[17];
  const float* W_att_vec   = (const float*)d_in[18];
  const float* W_r1        = (const float*)d_in[19];
  const float* b_r1        = (const float*)d_in[20];
  const float* W_r2        = (const float*)d_in[21];
  const float* b_r2        = (const float*)d_in[22];
  const float* W_col_in    = (const float*)d_in[23];
  const float* W_ptr       = (const float*)d_in[24];
  const float* w_mem       = (const float*)d_in[25];

  float* base = (float*)d_ws;
  size_t o = 0;
  float* h      = base + o; o += 131072;
  float* c      = base + o; o += 131072;
  float* att    = base + o; o += 131072;
  float* appear = base + o; o += 16384;
  float* acc    = base + o; o += 256;
  int zeroN = (int)o;                                   // 409,856
  ushort_t* hist_b  = (ushort_t*)(base + o); o += 3932160;  // 60*256*512 bf16
  ushort_t* colin_b = (ushort_t*)(base + o); o += 1048576;  // 16384*128 bf16
  float* xh     = base + o; o += 475136;
  float* gates  = base + o; o += 524288;
  float* attq   = base + o; o += 131072;
  float* ctx    = base + o; o += 131072;
  float* r1ptr  = base + o; o += 655360;                // [256][2560] = embh|ptrq
  float* embq   = base + o; o += 32768;
  ushort_t* WpG  = (ushort_t*)(base + o); o += 1900544; // 1856x2048
  ushort_t* WpQ  = (ushort_t*)(base + o); o += 131072;  // 512x512
  ushort_t* WpV  = (ushort_t*)(base + o); o += 262144;  // 1024x512
  ushort_t* WpRP = (ushort_t*)(base + o); o += 655360;  // 512x2560
  ushort_t* WpR2 = (ushort_t*)(base + o); o += 131072;  // 2048x128
  ushort_t* WpCI = (ushort_t*)(base + o); o += 32768;   // 512x128
  (void)ws_size; (void)in_sizes; (void)n_in; (void)out_size;

  zero_kernel<<<(zeroN + 255) / 256, 256, 0, stream>>>(base, zeroN);

  // weight packing (once per launch)
  pack_w<<<(1344 * 2048 + 255) / 256, 256, 0, stream>>>(W_ih,  WpG, 1344, 2048, 2048, 0, 0, 2048);
  pack_w<<<(512 * 2048 + 255) / 256, 256, 0, stream>>>(W_hh,  WpG,  512, 2048, 2048, 1344, 0, 2048);
  pack_w<<<(512 * 512 + 255) / 256, 256, 0, stream>>>(W_att_q, WpQ, 512, 512, 512, 0, 0, 512);
  pack_w<<<(1024 * 512 + 255) / 256, 256, 0, stream>>>(W_att_vec, WpV, 1024, 512, 512, 0, 0, 512);
  pack_w<<<(512 * 2048 + 255) / 256, 256, 0, stream>>>(W_r1,  WpRP, 512, 2048, 2560, 0, 0, 2048);
  pack_w<<<(512 * 512 + 255) / 256, 256, 0, stream>>>(W_ptr, WpRP, 512, 512, 2560, 0, 2048, 512);
  pack_w<<<(2048 * 128 + 255) / 256, 256, 0, stream>>>(W_r2,  WpR2, 2048, 128, 128, 0, 0, 128);
  pack_w<<<(512 * 128 + 255) / 256, 256, 0, stream>>>(W_col_in, WpCI, 512, 128, 128, 0, 0, 128);

  // colin = col_enc @ W_col_in -> bf16  (M=16384, K=512, N=128)
  gemm_bf16<<<dim3(2, 256), 256, 0, stream>>>(col_enc, nullptr, 512, 512, 0,
      WpCI, nullptr, 0, nullptr, colin_b, 128, 128, 512, 0);

  for (int t = 0; t < NT; ++t) {
    build_x_kernel<<<NB, 256, 0, stream>>>(xh, hist_b, h, att, colin_b, prod_embed,
        type_embed, action_kind, prod_ids, col_ids, parent_prod, parent_type,
        parent_time, tgt_lens, t);
    // gates = xh @ [W_ih;W_hh] + b_lstm   (256x1856x2048)
    gemm_bf16<<<dim3(32, 4), 256, 0, stream>>>(xh, nullptr, DXH, DXH, 0,
        WpG, b_lstm, DG, gates, nullptr, DG, DG, DXH, 0);
    lstm_kernel<<<NB * DRNN / 256, 256, 0, stream>>>(gates, c, h, hist_b, t);
    // attq = h @ W_att_q   (256x512x512)
    gemm_bf16<<<dim3(8, 4), 256, 0, stream>>>(h, nullptr, 512, 512, 0,
        WpQ, nullptr, 0, attq, nullptr, 512, 512, 512, 0);
    attn_kernel<<<NB, 256, 0, stream>>>(enc, attq, enc_lens, ctx);
    // att = tanh([ctx|h] @ W_att_vec)   (256x1024x512)
    gemm_bf16<<<dim3(8, 4), 256, 0, stream>>>(ctx, h, 512, 512, 512,
        WpV, nullptr, 0, att, nullptr, 512, 512, 1024, 512);
    // [embh|ptrq] = [tanh(att@W_r1+b_r1) | att@W_ptr]   (256x512x2560)
    gemm_bf16<<<dim3(40, 4), 256, 0, stream>>>(att, nullptr, 512, 512, 0,
        WpRP, b_r1, 2048, r1ptr, nullptr, 2560, 2560, 512, 2048);
    // embq = embh @ W_r2 + b_r2   (256x2048x128)
    gemm_bf16<<<dim3(2, 4), 256, 0, stream>>>(r1ptr, nullptr, 2048, 2560, 0,
        WpR2, b_r2, 128, embq, nullptr, 128, 128, 2048, 0);
    final_step_kernel<<<NB, 256, 0, stream>>>(embq, prod_embed, b_lin, att,
        r1ptr, col_enc, w_mem, col_lens, tgt_lens, action_kind, prod_ids,
        col_ids, appear, acc, t);
  }
  loss_kernel<<<1, 256, 0, stream>>>(acc, (float*)d_out);
}